// Round 1
// baseline (673.339 us; speedup 1.0000x reference)
//
#include <hip/hip_runtime.h>
#include <cfloat>
#include <cmath>

// ---------------- types ----------------
typedef __attribute__((ext_vector_type(8))) short bf16x8;   // 8 bf16 in 4 VGPRs (per cdna_hip_programming.md §3)
typedef __attribute__((ext_vector_type(4))) float f32x4;

__device__ __forceinline__ short f2bf(float f) {
    // fp32 -> bf16 round-to-nearest-even (inputs finite; no NaN handling needed)
    unsigned u = __float_as_uint(f);
    u += 0x7fffu + ((u >> 16) & 1u);
    return (short)(u >> 16);
}

__device__ __forceinline__ bf16x8 pack8(float4 p0, float4 p1) {
    bf16x8 r;
    r[0] = f2bf(p0.x); r[1] = f2bf(p0.y); r[2] = f2bf(p0.z); r[3] = f2bf(p0.w);
    r[4] = f2bf(p1.x); r[5] = f2bf(p1.y); r[6] = f2bf(p1.z); r[7] = f2bf(p1.w);
    return r;
}

// ---------------- problem sizes ----------------
#define BATCH 64
#define KDIM  150528          // 3*224*224
#define NEMB  512
#define HIN_W 812             // 512 + 300
#define HID   400
#define ROWS  192             // B*C
#define RLEN  50176           // 224*224
#define NBINS 100

// GEMM tiling: 147 K-chunks of 1024, N-tiles of 128 -> 588 blocks
#define NCHUNK 147
#define KC     1024
#define NTILE  128

// ---------------- ws layout (float offsets) ----------------
#define WS_MN   0                             // 192
#define WS_MX   192                           // 192
#define WS_HIN  384                           // 64*812 = 51968
#define WS_H    (WS_HIN + BATCH*HIN_W)        // 64*400 = 25600
#define WS_T    (WS_H + BATCH*HID)            // 64*1400 = 89600
#define WS_PART (WS_T + BATCH*1400)           // 147*64*512 = 4816896  (~19.3 MB)

// ================= K1: per-(b,c) min/max =================
__global__ __launch_bounds__(256) void k_minmax(const float* __restrict__ x, float* __restrict__ ws) {
    int row = blockIdx.x;
    const float4* p = (const float4*)(x + (size_t)row * RLEN);
    float mn = FLT_MAX, mx = -FLT_MAX;
    for (int i = threadIdx.x; i < RLEN / 4; i += 256) {   // 12544 = 49*256, exact
        float4 v = p[i];
        mn = fminf(mn, fminf(fminf(v.x, v.y), fminf(v.z, v.w)));
        mx = fmaxf(mx, fmaxf(fmaxf(v.x, v.y), fmaxf(v.z, v.w)));
    }
#pragma unroll
    for (int m = 1; m < 64; m <<= 1) {
        mn = fminf(mn, __shfl_xor(mn, m, 64));
        mx = fmaxf(mx, __shfl_xor(mx, m, 64));
    }
    __shared__ float smn[4], smx[4];
    int wave = threadIdx.x >> 6, lane = threadIdx.x & 63;
    if (lane == 0) { smn[wave] = mn; smx[wave] = mx; }
    __syncthreads();
    if (threadIdx.x == 0) {
        ws[WS_MN + row] = fminf(fminf(smn[0], smn[1]), fminf(smn[2], smn[3]));
        ws[WS_MX + row] = fmaxf(fmaxf(smx[0], smx[1]), fmaxf(smx[2], smx[3]));
    }
}

// ================= K2: histogram (torch.histc semantics), writes hist cols of h_in =================
__global__ __launch_bounds__(256) void k_hist(const float* __restrict__ x, float* __restrict__ ws) {
    int row = blockIdx.x; int b = row / 3, c = row % 3;
    float mn = ws[WS_MN + row], mx = ws[WS_MX + row];
    float width = (mx > mn) ? (mx - mn) : 1.0f;
    __shared__ unsigned bins[NBINS];
    if (threadIdx.x < NBINS) bins[threadIdx.x] = 0u;
    __syncthreads();
    const float4* p = (const float4*)(x + (size_t)row * RLEN);
    for (int i = threadIdx.x; i < RLEN / 4; i += 256) {
        float4 v = p[i];
        float e[4] = {v.x, v.y, v.z, v.w};
#pragma unroll
        for (int j = 0; j < 4; ++j) {
            // exact reference fp32 op sequence: (x-mn)/width*100 -> floor -> int -> clip
            int idx = (int)floorf((e[j] - mn) / width * 100.0f);
            idx = idx < 0 ? 0 : (idx > 99 ? 99 : idx);
            atomicAdd(&bins[idx], 1u);
        }
    }
    __syncthreads();
    if (threadIdx.x < NBINS)
        ws[WS_HIN + b * HIN_W + NEMB + c * NBINS + threadIdx.x] = (float)bins[threadIdx.x];
}

// ================= K3: big GEMM xm-partials = x @ base_W.T (split-K, bf16 MFMA) =================
// grid (147, 4), block 256. Block: K-chunk kc (1024), N-tile n0 (128 cols).
// Wave w: n-slice [n0+w*32, +32), all 64 m rows -> 4 m-tiles x 2 n-tiles of 16x16 acc.
__global__ __launch_bounds__(256) void k_gemm(const float* __restrict__ x, const float* __restrict__ W,
                                              float* __restrict__ part) {
    int kc = blockIdx.x;
    int n0 = blockIdx.y * NTILE;
    int wave = threadIdx.x >> 6, lane = threadIdx.x & 63;
    int l15 = lane & 15, quad = lane >> 4;
    size_t kbase = (size_t)kc * KC + (size_t)quad * 8;   // A[m][k=quad*8+j], B[n][k=quad*8+j]

    const float* arow[4];
#pragma unroll
    for (int mt = 0; mt < 4; ++mt) arow[mt] = x + (size_t)(mt * 16 + l15) * KDIM + kbase;
    const float* brow[2];
#pragma unroll
    for (int nt = 0; nt < 2; ++nt) brow[nt] = W + (size_t)(n0 + wave * 32 + nt * 16 + l15) * KDIM + kbase;

    f32x4 acc[4][2];
#pragma unroll
    for (int mt = 0; mt < 4; ++mt)
#pragma unroll
        for (int nt = 0; nt < 2; ++nt) acc[mt][nt] = (f32x4){0.f, 0.f, 0.f, 0.f};

#pragma unroll 2
    for (int ks = 0; ks < KC; ks += 32) {
        bf16x8 a[4], b[2];
#pragma unroll
        for (int mt = 0; mt < 4; ++mt) {
            float4 p0 = *(const float4*)(arow[mt] + ks);
            float4 p1 = *(const float4*)(arow[mt] + ks + 4);
            a[mt] = pack8(p0, p1);
        }
#pragma unroll
        for (int nt = 0; nt < 2; ++nt) {
            float4 p0 = *(const float4*)(brow[nt] + ks);
            float4 p1 = *(const float4*)(brow[nt] + ks + 4);
            b[nt] = pack8(p0, p1);
        }
#pragma unroll
        for (int mt = 0; mt < 4; ++mt)
#pragma unroll
            for (int nt = 0; nt < 2; ++nt)
                acc[mt][nt] = __builtin_amdgcn_mfma_f32_16x16x32_bf16(a[mt], b[nt], acc[mt][nt], 0, 0, 0);
    }

    // C/D layout: col = lane&15 (n), row = quad*4 + reg (m)   [m89/m91-verified]
    float* pb = part + (size_t)kc * (BATCH * NEMB);
#pragma unroll
    for (int mt = 0; mt < 4; ++mt)
#pragma unroll
        for (int nt = 0; nt < 2; ++nt) {
            int n = n0 + wave * 32 + nt * 16 + l15;
#pragma unroll
            for (int r = 0; r < 4; ++r) {
                int m = mt * 16 + quad * 4 + r;
                pb[m * NEMB + n] = acc[mt][nt][r];
            }
        }
}

// ================= K4: reduce split-K partials + bias -> h_in[:, :512] =================
__global__ __launch_bounds__(256) void k_reduce(const float* __restrict__ part, const float* __restrict__ bias,
                                                float* __restrict__ hin) {
    int o = blockIdx.x * 256 + threadIdx.x;   // 32768 outputs
    int m = o >> 9, n = o & 511;
    float s = bias[n];
    for (int c = 0; c < NCHUNK; ++c) s += part[(size_t)c * (BATCH * NEMB) + o];
    hin[m * HIN_W + n] = s;
}

// ================= K5: h = relu(h_in @ hW.T + hb) — one wave per output =================
__global__ __launch_bounds__(256) void k_layer1(const float* __restrict__ hin, const float* __restrict__ hW,
                                                const float* __restrict__ hb, float* __restrict__ h) {
    int wave = threadIdx.x >> 6, lane = threadIdx.x & 63;
    int gid = blockIdx.x * 4 + wave;           // 25600 outputs
    int b = gid / HID, j = gid - b * HID;
    const float* hr = hin + b * HIN_W;
    const float* wr = hW + j * HIN_W;
    float s = 0.f;
    for (int k = lane; k < HIN_W; k += 64) s += hr[k] * wr[k];
#pragma unroll
    for (int m = 1; m < 64; m <<= 1) s += __shfl_xor(s, m, 64);
    if (lane == 0) h[b * HID + j] = fmaxf(s + hb[j], 0.f);
}

// ================= K6: heads layer-1 (st600 | age400 | gen400 concat) =================
__global__ __launch_bounds__(256) void k_heads1(const float* __restrict__ h,
                                                const float* __restrict__ stW1, const float* __restrict__ stb1,
                                                const float* __restrict__ ageW1, const float* __restrict__ ageb1,
                                                const float* __restrict__ genW1, const float* __restrict__ genb1,
                                                float* __restrict__ t) {
    int wave = threadIdx.x >> 6, lane = threadIdx.x & 63;
    int gid = blockIdx.x * 4 + wave;           // 89600 outputs
    int b = gid / 1400, o = gid - b * 1400;
    const float* wr; float bias;
    if (o < 600)       { wr = stW1  + (size_t)o * 400;          bias = stb1[o]; }
    else if (o < 1000) { wr = ageW1 + (size_t)(o - 600) * 400;  bias = ageb1[o - 600]; }
    else               { wr = genW1 + (size_t)(o - 1000) * 400; bias = genb1[o - 1000]; }
    const float* hr = h + b * HID;
    float s = 0.f;
    for (int k = lane; k < 400; k += 64) s += hr[k] * wr[k];
#pragma unroll
    for (int m = 1; m < 64; m <<= 1) s += __shfl_xor(s, m, 64);
    if (lane == 0) t[b * 1400 + o] = fmaxf(s + bias, 0.f);
}

// ================= K7: heads layer-2 + relu + softmax -> d_out =================
__global__ __launch_bounds__(64) void k_heads2(const float* __restrict__ t,
                                               const float* __restrict__ stW2, const float* __restrict__ stb2,
                                               const float* __restrict__ ageW2, const float* __restrict__ ageb2,
                                               const float* __restrict__ genW2, const float* __restrict__ genb2,
                                               float* __restrict__ out) {
    int b = blockIdx.x;
    int lane = threadIdx.x;
    int o = lane >> 2, sub = lane & 3;         // 16 outputs x 4 lanes each
    const float* tr = t + b * 1400;
    const float* wr; const float* tb; float bias; int Klen;
    if (o < 10)      { wr = stW2  + o * 600;        tb = tr;        bias = stb2[o];      Klen = 600; }
    else if (o < 14) { wr = ageW2 + (o - 10) * 400; tb = tr + 600;  bias = ageb2[o - 10]; Klen = 400; }
    else             { wr = genW2 + (o - 14) * 400; tb = tr + 1000; bias = genb2[o - 14]; Klen = 400; }
    float s = 0.f;
    for (int k = sub; k < Klen; k += 4) s += tb[k] * wr[k];
    s += __shfl_xor(s, 1, 64);
    s += __shfl_xor(s, 2, 64);
    __shared__ float lg[16];
    if (sub == 0) lg[o] = fmaxf(s + bias, 0.f);   // relu(logits)
    __syncthreads();
    if (lane == 0) {        // softmax st -> out[0 + b*10 ..]
        float mx = lg[0];
        for (int i = 1; i < 10; ++i) mx = fmaxf(mx, lg[i]);
        float e[10], sum = 0.f;
        for (int i = 0; i < 10; ++i) { e[i] = expf(lg[i] - mx); sum += e[i]; }
        for (int i = 0; i < 10; ++i) out[b * 10 + i] = e[i] / sum;
    } else if (lane == 1) { // softmax age -> out[640 + b*4 ..]
        float mx = lg[10];
        for (int i = 1; i < 4; ++i) mx = fmaxf(mx, lg[10 + i]);
        float e[4], sum = 0.f;
        for (int i = 0; i < 4; ++i) { e[i] = expf(lg[10 + i] - mx); sum += e[i]; }
        for (int i = 0; i < 4; ++i) out[640 + b * 4 + i] = e[i] / sum;
    } else if (lane == 2) { // softmax gender -> out[896 + b*2 ..]
        float mx = fmaxf(lg[14], lg[15]);
        float e0 = expf(lg[14] - mx), e1 = expf(lg[15] - mx);
        float sum = e0 + e1;
        out[896 + b * 2 + 0] = e0 / sum;
        out[896 + b * 2 + 1] = e1 / sum;
    }
}

// ================= launch =================
extern "C" void kernel_launch(void* const* d_in, const int* in_sizes, int n_in,
                              void* d_out, int out_size, void* d_ws, size_t ws_size,
                              hipStream_t stream) {
    (void)in_sizes; (void)n_in; (void)out_size; (void)ws_size;
    const float* x      = (const float*)d_in[0];
    const float* base_W = (const float*)d_in[1];
    const float* base_b = (const float*)d_in[2];
    const float* hW     = (const float*)d_in[3];
    const float* hb     = (const float*)d_in[4];
    const float* stW1   = (const float*)d_in[5];
    const float* stb1   = (const float*)d_in[6];
    const float* stW2   = (const float*)d_in[7];
    const float* stb2   = (const float*)d_in[8];
    const float* ageW1  = (const float*)d_in[9];
    const float* ageb1  = (const float*)d_in[10];
    const float* ageW2  = (const float*)d_in[11];
    const float* ageb2  = (const float*)d_in[12];
    const float* genW1  = (const float*)d_in[13];
    const float* genb1  = (const float*)d_in[14];
    const float* genW2  = (const float*)d_in[15];
    const float* genb2  = (const float*)d_in[16];
    float* ws  = (float*)d_ws;
    float* out = (float*)d_out;

    k_minmax<<<ROWS, 256, 0, stream>>>(x, ws);
    k_hist  <<<ROWS, 256, 0, stream>>>(x, ws);
    k_gemm  <<<dim3(NCHUNK, NEMB / NTILE), 256, 0, stream>>>(x, base_W, ws + WS_PART);
    k_reduce<<<(BATCH * NEMB) / 256, 256, 0, stream>>>(ws + WS_PART, base_b, ws + WS_HIN);
    k_layer1<<<(BATCH * HID) / 4, 256, 0, stream>>>(ws + WS_HIN, hW, hb, ws + WS_H);
    k_heads1<<<(BATCH * 1400) / 4, 256, 0, stream>>>(ws + WS_H, stW1, stb1, ageW1, ageb1, genW1, genb1, ws + WS_T);
    k_heads2<<<BATCH, 64, 0, stream>>>(ws + WS_T, stW2, stb2, ageW2, ageb2, genW2, genb2, out);
}

// Round 2
// 588.033 us; speedup vs baseline: 1.1451x; 1.1451x over previous
//
#include <hip/hip_runtime.h>
#include <cfloat>
#include <cmath>

// ---------------- types ----------------
typedef __attribute__((ext_vector_type(8))) short bf16x8;   // 8 bf16 (4 VGPRs) — MFMA A/B frag
typedef __attribute__((ext_vector_type(4))) float f32x4;    // MFMA C/D frag

__device__ __forceinline__ short f2bf(float f) {
    // fp32 -> bf16 round-to-nearest-even (inputs finite)
    unsigned u = __float_as_uint(f);
    u += 0x7fffu + ((u >> 16) & 1u);
    return (short)(u >> 16);
}

// ---------------- problem sizes ----------------
#define BATCH 64
#define KDIM  150528          // 3*224*224
#define NEMB  512
#define HIN_W 812             // 512 + 300
#define HID   400
#define ROWS  192             // B*C
#define RLEN  50176           // 224*224
#define NBINS 100

// GEMM tiling: grid (147 K-chunks x 8 N-tiles of 64) = 1176 blocks
#define NCHUNK 147
#define KC     1024
#define NTILE  64
#define BK     64
#define NSLAB  (KC / BK)      // 16
#define LDA    72             // 64 + 8 bf16 pad: row stride 144 B == 4 banks shift -> 2-way (free)

// ---------------- ws layout (float offsets) ----------------
#define WS_HIN  0                             // 64*812 = 51968 (cols 0..511 from reduce, 512..811 from hist)
#define WS_H    (WS_HIN + BATCH*HIN_W)        // 64*400
#define WS_T    (WS_H + BATCH*HID)            // 64*1400
#define WS_PART (WS_T + BATCH*1400)           // 147*64*512 = 4816896 (~19.3 MB)

// ================= K1: fused per-(b,c) min/max + histogram (torch.histc semantics) =================
// 192 blocks x 1024 threads. Pass 1: min/max (HBM). Pass 2: bin (row LLC-hot). 4 shared-hist copies.
__global__ __launch_bounds__(1024) void k_hist(const float* __restrict__ x, float* __restrict__ ws) {
    int row = blockIdx.x; int b = row / 3, c = row % 3;
    int tid = threadIdx.x, lane = tid & 63, wave = tid >> 6;
    const float4* p = (const float4*)(x + (size_t)row * RLEN);

    float mn = FLT_MAX, mx = -FLT_MAX;
    for (int i = tid; i < RLEN / 4; i += 1024) {          // 12544 f4, ~12.25 iters
        float4 v = p[i];
        mn = fminf(mn, fminf(fminf(v.x, v.y), fminf(v.z, v.w)));
        mx = fmaxf(mx, fmaxf(fmaxf(v.x, v.y), fmaxf(v.z, v.w)));
    }
#pragma unroll
    for (int m = 1; m < 64; m <<= 1) {
        mn = fminf(mn, __shfl_xor(mn, m, 64));
        mx = fmaxf(mx, __shfl_xor(mx, m, 64));
    }
    __shared__ float smn[16], smx[16];
    __shared__ float bmn, bwidth;
    __shared__ unsigned bins[4][NBINS];
    if (lane == 0) { smn[wave] = mn; smx[wave] = mx; }
    for (int i = tid; i < 4 * NBINS; i += 1024) bins[i / NBINS][i % NBINS] = 0u;
    __syncthreads();
    if (tid == 0) {
        float a = smn[0], z = smx[0];
        for (int i = 1; i < 16; ++i) { a = fminf(a, smn[i]); z = fmaxf(z, smx[i]); }
        bmn = a;
        bwidth = (z > a) ? (z - a) : 1.0f;
    }
    __syncthreads();
    float lmn = bmn, lw = bwidth;
    unsigned* mybins = bins[wave & 3];
    for (int i = tid; i < RLEN / 4; i += 1024) {
        float4 v = p[i];
        float e[4] = {v.x, v.y, v.z, v.w};
#pragma unroll
        for (int j = 0; j < 4; ++j) {
            // exact reference fp32 op sequence: (x-mn)/width*100 -> floor -> int -> clip
            int idx = (int)floorf((e[j] - lmn) / lw * 100.0f);
            idx = idx < 0 ? 0 : (idx > 99 ? 99 : idx);
            atomicAdd(&mybins[idx], 1u);
        }
    }
    __syncthreads();
    if (tid < NBINS) {
        unsigned s = bins[0][tid] + bins[1][tid] + bins[2][tid] + bins[3][tid];
        ws[WS_HIN + b * HIN_W + NEMB + c * NBINS + tid] = (float)s;
    }
}

// ================= K2: big GEMM partials = x @ base_W.T (split-K, LDS-staged bf16 MFMA) =================
// grid (147, 8), block 256 = 4 waves. Block: K-chunk (1024 k), N-tile (64 cols), all 64 m.
// Slab = 64k. Stage fp32 coalesced -> convert bf16 -> padded LDS (double-buffered) -> MFMA.
__global__ __launch_bounds__(256, 4) void k_gemm(const float* __restrict__ x, const float* __restrict__ W,
                                                 float* __restrict__ part) {
    __shared__ short sA[2][64 * LDA];
    __shared__ short sB[2][64 * LDA];

    int kc = blockIdx.x;
    int n0 = blockIdx.y * NTILE;
    int tid = threadIdx.x;
    int wave = tid >> 6, lane = tid & 63;
    int l15 = lane & 15, quad = lane >> 4;

    // loader mapping: slab viewed as 64 rows x 16 float4 = 1024 slots; 4 passes of 256 threads.
    // lanes 0..15 -> f4 0..15 = 256B contiguous per row: fully dense coalescing.
    int lrow[4], lf4[4];
#pragma unroll
    for (int pp = 0; pp < 4; ++pp) { int slot = pp * 256 + tid; lrow[pp] = slot >> 4; lf4[pp] = slot & 15; }

    const float* Ab = x + (size_t)kc * KC;            // + row*KDIM + s*BK + f4*4
    const float* Bb = W + (size_t)(n0) * KDIM + (size_t)kc * KC;

    f32x4 acc[4];
#pragma unroll
    for (int mt = 0; mt < 4; ++mt) acc[mt] = (f32x4){0.f, 0.f, 0.f, 0.f};

    float4 pfA[4], pfB[4];
    // prologue: load slab 0
#pragma unroll
    for (int pp = 0; pp < 4; ++pp) {
        pfA[pp] = *(const float4*)(Ab + (size_t)lrow[pp] * KDIM + lf4[pp] * 4);
        pfB[pp] = *(const float4*)(Bb + (size_t)lrow[pp] * KDIM + lf4[pp] * 4);
    }
#pragma unroll
    for (int pp = 0; pp < 4; ++pp) {
        short4 a4 = make_short4(f2bf(pfA[pp].x), f2bf(pfA[pp].y), f2bf(pfA[pp].z), f2bf(pfA[pp].w));
        short4 b4 = make_short4(f2bf(pfB[pp].x), f2bf(pfB[pp].y), f2bf(pfB[pp].z), f2bf(pfB[pp].w));
        *(short4*)&sA[0][lrow[pp] * LDA + lf4[pp] * 4] = a4;
        *(short4*)&sB[0][lrow[pp] * LDA + lf4[pp] * 4] = b4;
    }
    __syncthreads();

    for (int s = 0; s < NSLAB; ++s) {
        int buf = s & 1;
        // issue next-slab global loads first: a full slab of compute hides their latency
        if (s + 1 < NSLAB) {
            const float* An = Ab + (s + 1) * BK;
            const float* Bn = Bb + (s + 1) * BK;
#pragma unroll
            for (int pp = 0; pp < 4; ++pp) {
                pfA[pp] = *(const float4*)(An + (size_t)lrow[pp] * KDIM + lf4[pp] * 4);
                pfB[pp] = *(const float4*)(Bn + (size_t)lrow[pp] * KDIM + lf4[pp] * 4);
            }
        }
        // compute current slab from LDS
#pragma unroll
        for (int ks = 0; ks < 2; ++ks) {
            bf16x8 bf = *(const bf16x8*)&sB[buf][(wave * 16 + l15) * LDA + ks * 32 + quad * 8];
#pragma unroll
            for (int mt = 0; mt < 4; ++mt) {
                bf16x8 af = *(const bf16x8*)&sA[buf][(mt * 16 + l15) * LDA + ks * 32 + quad * 8];
                acc[mt] = __builtin_amdgcn_mfma_f32_16x16x32_bf16(af, bf, acc[mt], 0, 0, 0);
            }
        }
        // convert + write next slab into the other buffer
        if (s + 1 < NSLAB) {
            int nbuf = buf ^ 1;
#pragma unroll
            for (int pp = 0; pp < 4; ++pp) {
                short4 a4 = make_short4(f2bf(pfA[pp].x), f2bf(pfA[pp].y), f2bf(pfA[pp].z), f2bf(pfA[pp].w));
                short4 b4 = make_short4(f2bf(pfB[pp].x), f2bf(pfB[pp].y), f2bf(pfB[pp].z), f2bf(pfB[pp].w));
                *(short4*)&sA[nbuf][lrow[pp] * LDA + lf4[pp] * 4] = a4;
                *(short4*)&sB[nbuf][lrow[pp] * LDA + lf4[pp] * 4] = b4;
            }
        }
        __syncthreads();
    }

    // C/D layout: col = lane&15 (n), row = quad*4 + reg (m)   [m89/m91-verified; round-1 validated]
    float* pb = part + (size_t)kc * (BATCH * NEMB);
#pragma unroll
    for (int mt = 0; mt < 4; ++mt) {
        int n = n0 + wave * 16 + l15;
#pragma unroll
        for (int r = 0; r < 4; ++r) {
            int m = mt * 16 + quad * 4 + r;
            pb[m * NEMB + n] = acc[mt][r];
        }
    }
}

// ================= K3: reduce split-K partials + bias -> h_in[:, :512] =================
// 1024 blocks x 256. 8 slices per output: each thread sums ~18 chunks (pipelined), LDS tree.
__global__ __launch_bounds__(256) void k_reduce(const float* __restrict__ part, const float* __restrict__ bias,
                                                float* __restrict__ hin) {
    __shared__ float sm[256];
    int tid = threadIdx.x;
    int o = blockIdx.x * 32 + (tid & 31);     // 32768 outputs
    int slice = tid >> 5;                     // 0..7
    float s = 0.f;
    for (int c = slice; c < NCHUNK; c += 8) s += part[(size_t)c * (BATCH * NEMB) + o];
    sm[tid] = s;
    __syncthreads();
    if (tid < 32) {
        float t = sm[tid];
#pragma unroll
        for (int sl = 1; sl < 8; ++sl) t += sm[sl * 32 + tid];
        int m = o >> 9, n = o & 511;
        hin[m * HIN_W + n] = t + bias[n];
    }
}

// ================= K4: h = relu(h_in @ hW.T + hb) — one wave per output =================
__global__ __launch_bounds__(256) void k_layer1(const float* __restrict__ hin, const float* __restrict__ hW,
                                                const float* __restrict__ hb, float* __restrict__ h) {
    int wave = threadIdx.x >> 6, lane = threadIdx.x & 63;
    int gid = blockIdx.x * 4 + wave;           // 25600 outputs
    int b = gid / HID, j = gid - b * HID;
    const float* hr = hin + b * HIN_W;
    const float* wr = hW + j * HIN_W;
    float s = 0.f;
    for (int k = lane; k < HIN_W; k += 64) s += hr[k] * wr[k];
#pragma unroll
    for (int m = 1; m < 64; m <<= 1) s += __shfl_xor(s, m, 64);
    if (lane == 0) h[b * HID + j] = fmaxf(s + hb[j], 0.f);
}

// ================= K5: heads layer-1 (st600 | age400 | gen400 concat) =================
__global__ __launch_bounds__(256) void k_heads1(const float* __restrict__ h,
                                                const float* __restrict__ stW1, const float* __restrict__ stb1,
                                                const float* __restrict__ ageW1, const float* __restrict__ ageb1,
                                                const float* __restrict__ genW1, const float* __restrict__ genb1,
                                                float* __restrict__ t) {
    int wave = threadIdx.x >> 6, lane = threadIdx.x & 63;
    int gid = blockIdx.x * 4 + wave;           // 89600 outputs
    int b = gid / 1400, o = gid - b * 1400;
    const float* wr; float bias;
    if (o < 600)       { wr = stW1  + (size_t)o * 400;          bias = stb1[o]; }
    else if (o < 1000) { wr = ageW1 + (size_t)(o - 600) * 400;  bias = ageb1[o - 600]; }
    else               { wr = genW1 + (size_t)(o - 1000) * 400; bias = genb1[o - 1000]; }
    const float* hr = h + b * HID;
    float s = 0.f;
    for (int k = lane; k < 400; k += 64) s += hr[k] * wr[k];
#pragma unroll
    for (int m = 1; m < 64; m <<= 1) s += __shfl_xor(s, m, 64);
    if (lane == 0) t[b * 1400 + o] = fmaxf(s + bias, 0.f);
}

// ================= K6: heads layer-2 + relu + softmax -> d_out =================
__global__ __launch_bounds__(64) void k_heads2(const float* __restrict__ t,
                                               const float* __restrict__ stW2, const float* __restrict__ stb2,
                                               const float* __restrict__ ageW2, const float* __restrict__ ageb2,
                                               const float* __restrict__ genW2, const float* __restrict__ genb2,
                                               float* __restrict__ out) {
    int b = blockIdx.x;
    int lane = threadIdx.x;
    int o = lane >> 2, sub = lane & 3;         // 16 outputs x 4 lanes each
    const float* tr = t + b * 1400;
    const float* wr; const float* tb; float bias; int Klen;
    if (o < 10)      { wr = stW2  + o * 600;        tb = tr;        bias = stb2[o];      Klen = 600; }
    else if (o < 14) { wr = ageW2 + (o - 10) * 400; tb = tr + 600;  bias = ageb2[o - 10]; Klen = 400; }
    else             { wr = genW2 + (o - 14) * 400; tb = tr + 1000; bias = genb2[o - 14]; Klen = 400; }
    float s = 0.f;
    for (int k = sub; k < Klen; k += 4) s += tb[k] * wr[k];
    s += __shfl_xor(s, 1, 64);
    s += __shfl_xor(s, 2, 64);
    __shared__ float lg[16];
    if (sub == 0) lg[o] = fmaxf(s + bias, 0.f);   // relu(logits)
    __syncthreads();
    if (lane == 0) {        // softmax st -> out[b*10]
        float mx = lg[0];
        for (int i = 1; i < 10; ++i) mx = fmaxf(mx, lg[i]);
        float e[10], sum = 0.f;
        for (int i = 0; i < 10; ++i) { e[i] = expf(lg[i] - mx); sum += e[i]; }
        for (int i = 0; i < 10; ++i) out[b * 10 + i] = e[i] / sum;
    } else if (lane == 1) { // softmax age -> out[640 + b*4]
        float mx = lg[10];
        for (int i = 1; i < 4; ++i) mx = fmaxf(mx, lg[10 + i]);
        float e[4], sum = 0.f;
        for (int i = 0; i < 4; ++i) { e[i] = expf(lg[10 + i] - mx); sum += e[i]; }
        for (int i = 0; i < 4; ++i) out[640 + b * 4 + i] = e[i] / sum;
    } else if (lane == 2) { // softmax gender -> out[896 + b*2]
        float mx = fmaxf(lg[14], lg[15]);
        float e0 = expf(lg[14] - mx), e1 = expf(lg[15] - mx);
        float sum = e0 + e1;
        out[896 + b * 2 + 0] = e0 / sum;
        out[896 + b * 2 + 1] = e1 / sum;
    }
}

// ================= launch =================
extern "C" void kernel_launch(void* const* d_in, const int* in_sizes, int n_in,
                              void* d_out, int out_size, void* d_ws, size_t ws_size,
                              hipStream_t stream) {
    (void)in_sizes; (void)n_in; (void)out_size; (void)ws_size;
    const float* x      = (const float*)d_in[0];
    const float* base_W = (const float*)d_in[1];
    const float* base_b = (const float*)d_in[2];
    const float* hW     = (const float*)d_in[3];
    const float* hb     = (const float*)d_in[4];
    const float* stW1   = (const float*)d_in[5];
    const float* stb1   = (const float*)d_in[6];
    const float* stW2   = (const float*)d_in[7];
    const float* stb2   = (const float*)d_in[8];
    const float* ageW1  = (const float*)d_in[9];
    const float* ageb1  = (const float*)d_in[10];
    const float* ageW2  = (const float*)d_in[11];
    const float* ageb2  = (const float*)d_in[12];
    const float* genW1  = (const float*)d_in[13];
    const float* genb1  = (const float*)d_in[14];
    const float* genW2  = (const float*)d_in[15];
    const float* genb2  = (const float*)d_in[16];
    float* ws  = (float*)d_ws;
    float* out = (float*)d_out;

    k_hist  <<<ROWS, 1024, 0, stream>>>(x, ws);
    k_gemm  <<<dim3(NCHUNK, NEMB / NTILE), 256, 0, stream>>>(x, base_W, ws + WS_PART);
    k_reduce<<<(BATCH * NEMB) / 32, 256, 0, stream>>>(ws + WS_PART, base_b, ws + WS_HIN);
    k_layer1<<<(BATCH * HID) / 4, 256, 0, stream>>>(ws + WS_HIN, hW, hb, ws + WS_H);
    k_heads1<<<(BATCH * 1400) / 4, 256, 0, stream>>>(ws + WS_H, stW1, stb1, ageW1, ageb1, genW1, genb1, ws + WS_T);
    k_heads2<<<BATCH, 64, 0, stream>>>(ws + WS_T, stW2, stb2, ageW2, ageb2, genW2, genb2, out);
}

// Round 3
// 566.326 us; speedup vs baseline: 1.1890x; 1.0383x over previous
//
#include <hip/hip_runtime.h>
#include <cfloat>
#include <cmath>

// ---------------- types ----------------
typedef __attribute__((ext_vector_type(8))) short bf16x8;   // 8 bf16 (4 VGPRs) — MFMA A/B frag
typedef __attribute__((ext_vector_type(4))) float f32x4;    // MFMA C/D frag

__device__ __forceinline__ short f2bf(float f) {
    // fp32 -> bf16 round-to-nearest-even (inputs finite)
    unsigned u = __float_as_uint(f);
    u += 0x7fffu + ((u >> 16) & 1u);
    return (short)(u >> 16);
}

// ---------------- problem sizes ----------------
#define BATCH 64
#define KDIM  150528          // 3*224*224
#define NEMB  512
#define HIN_W 812             // 512 + 300
#define HID   400
#define ROWS  192             // B*C
#define RLEN  50176           // 224*224
#define NBINS 100

// GEMM tiling: grid (147 K-chunks x 8 N-tiles of 64) = 1176 blocks
#define NCHUNK 147
#define KC     1024
#define NTILE  64
#define BK     64
#define NSLAB  (KC / BK)      // 16
#define LDA    72             // 64 + 8 bf16 pad: 144 B row stride -> conflict-free b128 frag reads

// ---------------- ws layout (float offsets) ----------------
#define WS_HIN  0                             // 64*812 = 51968
#define WS_H    (WS_HIN + BATCH*HIN_W)        // 64*400 = 25600
#define WS_T    (WS_H + BATCH*HID)            // 64*1400 = 89600
#define WS_PART (WS_T + BATCH*1400)           // 147*64*512 = 4816896 (~19.3 MB)
#define WS_XBF  (WS_PART + NCHUNK*BATCH*NEMB) // bf16 copy of x: 192*50176 shorts = 4816896 floats

// ================= K1: fused min/max + histogram + bf16(x) emit =================
// 192 blocks x 1024 threads. Pass 1: min/max (HBM). Pass 2 (row LLC-hot): bin + write bf16(x).
__global__ __launch_bounds__(1024) void k_hist(const float* __restrict__ x, float* __restrict__ ws) {
    int row = blockIdx.x; int b = row / 3, c = row % 3;
    int tid = threadIdx.x, lane = tid & 63, wave = tid >> 6;
    const float4* p = (const float4*)(x + (size_t)row * RLEN);
    short* xbf = (short*)(ws + WS_XBF);

    float mn = FLT_MAX, mx = -FLT_MAX;
    for (int i = tid; i < RLEN / 4; i += 1024) {          // 12544 f4
        float4 v = p[i];
        mn = fminf(mn, fminf(fminf(v.x, v.y), fminf(v.z, v.w)));
        mx = fmaxf(mx, fmaxf(fmaxf(v.x, v.y), fmaxf(v.z, v.w)));
    }
#pragma unroll
    for (int m = 1; m < 64; m <<= 1) {
        mn = fminf(mn, __shfl_xor(mn, m, 64));
        mx = fmaxf(mx, __shfl_xor(mx, m, 64));
    }
    __shared__ float smn[16], smx[16];
    __shared__ float bmn, bwidth;
    __shared__ unsigned bins[4][NBINS];
    if (lane == 0) { smn[wave] = mn; smx[wave] = mx; }
    for (int i = tid; i < 4 * NBINS; i += 1024) bins[i / NBINS][i % NBINS] = 0u;
    __syncthreads();
    if (tid == 0) {
        float a = smn[0], z = smx[0];
        for (int i = 1; i < 16; ++i) { a = fminf(a, smn[i]); z = fmaxf(z, smx[i]); }
        bmn = a;
        bwidth = (z > a) ? (z - a) : 1.0f;
    }
    __syncthreads();
    float lmn = bmn, lw = bwidth;
    unsigned* mybins = bins[wave & 3];
    short* xrow = xbf + (size_t)row * RLEN;
    for (int i = tid; i < RLEN / 4; i += 1024) {
        float4 v = p[i];
        float e[4] = {v.x, v.y, v.z, v.w};
#pragma unroll
        for (int j = 0; j < 4; ++j) {
            // exact reference fp32 op sequence: (x-mn)/width*100 -> floor -> int -> clip
            int idx = (int)floorf((e[j] - lmn) / lw * 100.0f);
            idx = idx < 0 ? 0 : (idx > 99 ? 99 : idx);
            atomicAdd(&mybins[idx], 1u);
        }
        // emit bf16(x) for the GEMM A-operand (same RNE bits as before)
        *(short4*)&xrow[4 * i] = make_short4(f2bf(v.x), f2bf(v.y), f2bf(v.z), f2bf(v.w));
    }
    __syncthreads();
    if (tid < NBINS) {
        unsigned s = bins[0][tid] + bins[1][tid] + bins[2][tid] + bins[3][tid];
        ws[WS_HIN + b * HIN_W + NEMB + c * NBINS + tid] = (float)s;
    }
}

// ================= K2: GEMM partials = A(bf16) @ base_W.T (split-K, LDS-staged bf16 MFMA) =================
// grid (147, 8), block 256 = 4 waves. A pre-converted bf16 (from k_hist); B fp32 -> convert inline.
__global__ __launch_bounds__(256, 4) void k_gemm(const float* __restrict__ ws_all, const float* __restrict__ W,
                                                 float* __restrict__ part) {
    __shared__ short sA[2][64 * LDA];
    __shared__ short sB[2][64 * LDA];

    int kc = blockIdx.x;
    int n0 = blockIdx.y * NTILE;
    int tid = threadIdx.x;
    int wave = tid >> 6, lane = tid & 63;
    int l15 = lane & 15, quad = lane >> 4;

    const short* Abf = (const short*)(ws_all + WS_XBF);

    // A loader: slab = 64 rows x 8 slots of 8 shorts (16B); 512 slots, 2 passes of 256.
    int arow[2], acol[2];
#pragma unroll
    for (int pp = 0; pp < 2; ++pp) { int slot = pp * 256 + tid; arow[pp] = slot >> 3; acol[pp] = slot & 7; }
    // B loader: slab = 64 rows x 16 float4; 1024 slots, 4 passes of 256.
    int brow[4], bf4[4];
#pragma unroll
    for (int pp = 0; pp < 4; ++pp) { int slot = pp * 256 + tid; brow[pp] = slot >> 4; bf4[pp] = slot & 15; }

    const short* Ab = Abf + (size_t)kc * KC;                           // + row*KDIM + s*BK + col*8
    const float* Bb = W + (size_t)n0 * KDIM + (size_t)kc * KC;         // + row*KDIM + s*BK + f4*4

    f32x4 acc[4];
#pragma unroll
    for (int mt = 0; mt < 4; ++mt) acc[mt] = (f32x4){0.f, 0.f, 0.f, 0.f};

    bf16x8 pfA[2];
    float4 pfB[4];
    // prologue: slab 0
#pragma unroll
    for (int pp = 0; pp < 2; ++pp)
        pfA[pp] = *(const bf16x8*)(Ab + (size_t)arow[pp] * KDIM + acol[pp] * 8);
#pragma unroll
    for (int pp = 0; pp < 4; ++pp)
        pfB[pp] = *(const float4*)(Bb + (size_t)brow[pp] * KDIM + bf4[pp] * 4);
#pragma unroll
    for (int pp = 0; pp < 2; ++pp)
        *(bf16x8*)&sA[0][arow[pp] * LDA + acol[pp] * 8] = pfA[pp];
#pragma unroll
    for (int pp = 0; pp < 4; ++pp)
        *(short4*)&sB[0][brow[pp] * LDA + bf4[pp] * 4] =
            make_short4(f2bf(pfB[pp].x), f2bf(pfB[pp].y), f2bf(pfB[pp].z), f2bf(pfB[pp].w));
    __syncthreads();

    for (int s = 0; s < NSLAB; ++s) {
        int buf = s & 1;
        if (s + 1 < NSLAB) {   // issue next-slab loads: a full slab of compute hides them
            const short* An = Ab + (s + 1) * BK;
            const float* Bn = Bb + (s + 1) * BK;
#pragma unroll
            for (int pp = 0; pp < 2; ++pp)
                pfA[pp] = *(const bf16x8*)(An + (size_t)arow[pp] * KDIM + acol[pp] * 8);
#pragma unroll
            for (int pp = 0; pp < 4; ++pp)
                pfB[pp] = *(const float4*)(Bn + (size_t)brow[pp] * KDIM + bf4[pp] * 4);
        }
#pragma unroll
        for (int ks = 0; ks < 2; ++ks) {
            bf16x8 bf = *(const bf16x8*)&sB[buf][(wave * 16 + l15) * LDA + ks * 32 + quad * 8];
#pragma unroll
            for (int mt = 0; mt < 4; ++mt) {
                bf16x8 af = *(const bf16x8*)&sA[buf][(mt * 16 + l15) * LDA + ks * 32 + quad * 8];
                acc[mt] = __builtin_amdgcn_mfma_f32_16x16x32_bf16(af, bf, acc[mt], 0, 0, 0);
            }
        }
        if (s + 1 < NSLAB) {
            int nbuf = buf ^ 1;
#pragma unroll
            for (int pp = 0; pp < 2; ++pp)
                *(bf16x8*)&sA[nbuf][arow[pp] * LDA + acol[pp] * 8] = pfA[pp];
#pragma unroll
            for (int pp = 0; pp < 4; ++pp)
                *(short4*)&sB[nbuf][brow[pp] * LDA + bf4[pp] * 4] =
                    make_short4(f2bf(pfB[pp].x), f2bf(pfB[pp].y), f2bf(pfB[pp].z), f2bf(pfB[pp].w));
        }
        __syncthreads();
    }

    // C/D layout: col = lane&15 (n), row = quad*4 + reg (m)   [round-1/2 validated]
    float* pb = part + (size_t)kc * (BATCH * NEMB);
#pragma unroll
    for (int mt = 0; mt < 4; ++mt) {
        int n = n0 + wave * 16 + l15;
#pragma unroll
        for (int r = 0; r < 4; ++r) {
            int m = mt * 16 + quad * 4 + r;
            pb[m * NEMB + n] = acc[mt][r];
        }
    }
}

// ================= K3: reduce split-K partials + bias -> h_in[:, :512] =================
__global__ __launch_bounds__(256) void k_reduce(const float* __restrict__ part, const float* __restrict__ bias,
                                                float* __restrict__ hin) {
    __shared__ float sm[256];
    int tid = threadIdx.x;
    int o = blockIdx.x * 32 + (tid & 31);     // 32768 outputs
    int slice = tid >> 5;                     // 0..7
    float s = 0.f;
    for (int c = slice; c < NCHUNK; c += 8) s += part[(size_t)c * (BATCH * NEMB) + o];
    sm[tid] = s;
    __syncthreads();
    if (tid < 32) {
        float t = sm[tid];
#pragma unroll
        for (int sl = 1; sl < 8; ++sl) t += sm[sl * 32 + tid];
        int m = o >> 9, n = o & 511;
        hin[m * HIN_W + n] = t + bias[n];
    }
}

// ================= K4: h = relu(h_in @ hW.T + hb) — one wave per output =================
__global__ __launch_bounds__(256) void k_layer1(const float* __restrict__ hin, const float* __restrict__ hW,
                                                const float* __restrict__ hb, float* __restrict__ h) {
    int wave = threadIdx.x >> 6, lane = threadIdx.x & 63;
    int gid = blockIdx.x * 4 + wave;           // 25600 outputs
    int b = gid / HID, j = gid - b * HID;
    const float* hr = hin + b * HIN_W;
    const float* wr = hW + j * HIN_W;
    float s = 0.f;
    for (int k = lane; k < HIN_W; k += 64) s += hr[k] * wr[k];
#pragma unroll
    for (int m = 1; m < 64; m <<= 1) s += __shfl_xor(s, m, 64);
    if (lane == 0) h[b * HID + j] = fmaxf(s + hb[j], 0.f);
}

// ================= K5: heads layer-1 (st600 | age400 | gen400 concat) =================
__global__ __launch_bounds__(256) void k_heads1(const float* __restrict__ h,
                                                const float* __restrict__ stW1, const float* __restrict__ stb1,
                                                const float* __restrict__ ageW1, const float* __restrict__ ageb1,
                                                const float* __restrict__ genW1, const float* __restrict__ genb1,
                                                float* __restrict__ t) {
    int wave = threadIdx.x >> 6, lane = threadIdx.x & 63;
    int gid = blockIdx.x * 4 + wave;           // 89600 outputs
    int b = gid / 1400, o = gid - b * 1400;
    const float* wr; float bias;
    if (o < 600)       { wr = stW1  + (size_t)o * 400;          bias = stb1[o]; }
    else if (o < 1000) { wr = ageW1 + (size_t)(o - 600) * 400;  bias = ageb1[o - 600]; }
    else               { wr = genW1 + (size_t)(o - 1000) * 400; bias = genb1[o - 1000]; }
    const float* hr = h + b * HID;
    float s = 0.f;
    for (int k = lane; k < 400; k += 64) s += hr[k] * wr[k];
#pragma unroll
    for (int m = 1; m < 64; m <<= 1) s += __shfl_xor(s, m, 64);
    if (lane == 0) t[b * 1400 + o] = fmaxf(s + bias, 0.f);
}

// ================= K6: heads layer-2 + relu + softmax -> d_out =================
// 64 blocks x 256: 16 outputs x 16 lanes each.
__global__ __launch_bounds__(256) void k_heads2(const float* __restrict__ t,
                                                const float* __restrict__ stW2, const float* __restrict__ stb2,
                                                const float* __restrict__ ageW2, const float* __restrict__ ageb2,
                                                const float* __restrict__ genW2, const float* __restrict__ genb2,
                                                float* __restrict__ out) {
    int b = blockIdx.x;
    int tid = threadIdx.x;
    int o = tid >> 4, sub = tid & 15;          // 16 outputs x 16 lanes
    const float* tr = t + b * 1400;
    const float* wr; const float* tb; float bias; int Klen;
    if (o < 10)      { wr = stW2  + o * 600;        tb = tr;        bias = stb2[o];       Klen = 600; }
    else if (o < 14) { wr = ageW2 + (o - 10) * 400; tb = tr + 600;  bias = ageb2[o - 10]; Klen = 400; }
    else             { wr = genW2 + (o - 14) * 400; tb = tr + 1000; bias = genb2[o - 14]; Klen = 400; }
    float s = 0.f;
    for (int k = sub; k < Klen; k += 16) s += tb[k] * wr[k];
#pragma unroll
    for (int m = 1; m < 16; m <<= 1) s += __shfl_xor(s, m, 64);   // xor within aligned 16-lane group
    __shared__ float lg[16];
    if (sub == 0) lg[o] = fmaxf(s + bias, 0.f);   // relu(logits)
    __syncthreads();
    if (tid == 0) {         // softmax st -> out[b*10]
        float mx = lg[0];
        for (int i = 1; i < 10; ++i) mx = fmaxf(mx, lg[i]);
        float e[10], sum = 0.f;
        for (int i = 0; i < 10; ++i) { e[i] = expf(lg[i] - mx); sum += e[i]; }
        for (int i = 0; i < 10; ++i) out[b * 10 + i] = e[i] / sum;
    } else if (tid == 1) {  // softmax age -> out[640 + b*4]
        float mx = lg[10];
        for (int i = 1; i < 4; ++i) mx = fmaxf(mx, lg[10 + i]);
        float e[4], sum = 0.f;
        for (int i = 0; i < 4; ++i) { e[i] = expf(lg[10 + i] - mx); sum += e[i]; }
        for (int i = 0; i < 4; ++i) out[640 + b * 4 + i] = e[i] / sum;
    } else if (tid == 2) {  // softmax gender -> out[896 + b*2]
        float mx = fmaxf(lg[14], lg[15]);
        float e0 = expf(lg[14] - mx), e1 = expf(lg[15] - mx);
        float sum = e0 + e1;
        out[896 + b * 2 + 0] = e0 / sum;
        out[896 + b * 2 + 1] = e1 / sum;
    }
}

// ================= launch =================
extern "C" void kernel_launch(void* const* d_in, const int* in_sizes, int n_in,
                              void* d_out, int out_size, void* d_ws, size_t ws_size,
                              hipStream_t stream) {
    (void)in_sizes; (void)n_in; (void)out_size; (void)ws_size;
    const float* x      = (const float*)d_in[0];
    const float* base_W = (const float*)d_in[1];
    const float* base_b = (const float*)d_in[2];
    const float* hW     = (const float*)d_in[3];
    const float* hb     = (const float*)d_in[4];
    const float* stW1   = (const float*)d_in[5];
    const float* stb1   = (const float*)d_in[6];
    const float* stW2   = (const float*)d_in[7];
    const float* stb2   = (const float*)d_in[8];
    const float* ageW1  = (const float*)d_in[9];
    const float* ageb1  = (const float*)d_in[10];
    const float* ageW2  = (const float*)d_in[11];
    const float* ageb2  = (const float*)d_in[12];
    const float* genW1  = (const float*)d_in[13];
    const float* genb1  = (const float*)d_in[14];
    const float* genW2  = (const float*)d_in[15];
    const float* genb2  = (const float*)d_in[16];
    float* ws  = (float*)d_ws;
    float* out = (float*)d_out;

    k_hist  <<<ROWS, 1024, 0, stream>>>(x, ws);
    k_gemm  <<<dim3(NCHUNK, NEMB / NTILE), 256, 0, stream>>>(ws, base_W, ws + WS_PART);
    k_reduce<<<(BATCH * NEMB) / 32, 256, 0, stream>>>(ws + WS_PART, base_b, ws + WS_HIN);
    k_layer1<<<(BATCH * HID) / 4, 256, 0, stream>>>(ws + WS_HIN, hW, hb, ws + WS_H);
    k_heads1<<<(BATCH * 1400) / 4, 256, 0, stream>>>(ws + WS_H, stW1, stb1, ageW1, ageb1, genW1, genb1, ws + WS_T);
    k_heads2<<<BATCH, 256, 0, stream>>>(ws + WS_T, stW2, stb2, ageW2, ageb2, genW2, genb2, out);
}

// Round 4
// 559.771 us; speedup vs baseline: 1.2029x; 1.0117x over previous
//
#include <hip/hip_runtime.h>
#include <cfloat>
#include <cmath>

// ---------------- types ----------------
typedef __attribute__((ext_vector_type(8))) short bf16x8;   // 8 bf16 (4 VGPRs) — MFMA A/B frag
typedef __attribute__((ext_vector_type(4))) float f32x4;    // MFMA C/D frag

__device__ __forceinline__ short f2bf(float f) {
    // fp32 -> bf16 round-to-nearest-even (inputs finite)
    unsigned u = __float_as_uint(f);
    u += 0x7fffu + ((u >> 16) & 1u);
    return (short)(u >> 16);
}

// ---------------- problem sizes ----------------
#define BATCH 64
#define KDIM  150528          // 3*224*224
#define NEMB  512
#define HIN_W 812             // 512 + 300
#define HID   400
#define ROWS  192             // B*C
#define RLEN  50176           // 224*224
#define NBINS 100
#define SEGS  8               // row segments for minmax/hist kernels
#define SEGF4 1568            // (RLEN/4)/SEGS

// GEMM tiling: grid (112 K-chunks x 8 N-tiles of 64) = 896 blocks -> ALL co-resident at 4/CU
#define NCHUNK 112
#define KC     1344
#define NTILE  64
#define BK     64
#define NSLAB  (KC / BK)      // 21
#define LDA    72             // 64 + 8 bf16 pad: 144 B row stride -> conflict-free b128 frag reads

// ---------------- ws layout (float offsets) ----------------
#define WS_HIN  0                             // 64*812 = 51968
#define WS_H    (WS_HIN + BATCH*HIN_W)        // 64*400 = 25600
#define WS_T    (WS_H + BATCH*HID)            // 64*1400 = 89600
#define WS_MM   (WS_T + BATCH*1400)           // 384 uints: mn[192], mx[192]
#define WS_GB   (WS_MM + 2*ROWS)              // 192*100 uint global bins
#define WS_PART (WS_GB + ROWS*NBINS)          // 112*64*512 = 3670016 floats (~14.7 MB)
#define WS_XBF  (WS_PART + NCHUNK*BATCH*NEMB) // bf16 x: 192*50176 shorts = 4816896 floats

// ================= K0: init atomic targets (ws is poisoned 0xAA every call) =================
__global__ __launch_bounds__(256) void k_init(float* __restrict__ ws) {
    unsigned* mm = (unsigned*)(ws + WS_MM);
    unsigned* gb = (unsigned*)(ws + WS_GB);
    int i = blockIdx.x * 256 + threadIdx.x;
    if (i < ROWS) { mm[i] = 0x7F800000u; mm[ROWS + i] = 0u; }   // mn=+inf, mx=0.0f (x>=0)
    if (i < ROWS * NBINS) gb[i] = 0u;
}

// ================= K1: per-(b,c) min/max — full-GPU, atomic combine =================
// x uniform[0,1): non-negative floats => uint bit order == float order.
__global__ __launch_bounds__(256) void k_minmax(const float* __restrict__ x, float* __restrict__ ws) {
    int row = blockIdx.x >> 3, seg = blockIdx.x & 7;
    int tid = threadIdx.x, lane = tid & 63, wave = tid >> 6;
    const float4* p = (const float4*)(x + (size_t)row * RLEN) + seg * SEGF4;
    float mn = FLT_MAX, mx = -FLT_MAX;
    for (int i = tid; i < SEGF4; i += 256) {
        float4 v = p[i];
        mn = fminf(mn, fminf(fminf(v.x, v.y), fminf(v.z, v.w)));
        mx = fmaxf(mx, fmaxf(fmaxf(v.x, v.y), fmaxf(v.z, v.w)));
    }
#pragma unroll
    for (int m = 1; m < 64; m <<= 1) {
        mn = fminf(mn, __shfl_xor(mn, m, 64));
        mx = fmaxf(mx, __shfl_xor(mx, m, 64));
    }
    __shared__ float smn[4], smx[4];
    if (lane == 0) { smn[wave] = mn; smx[wave] = mx; }
    __syncthreads();
    if (tid == 0) {
        mn = fminf(fminf(smn[0], smn[1]), fminf(smn[2], smn[3]));
        mx = fmaxf(fmaxf(smx[0], smx[1]), fmaxf(smx[2], smx[3]));
        unsigned* mm = (unsigned*)(ws + WS_MM);
        atomicMin(&mm[row], __float_as_uint(mn));
        atomicMax(&mm[ROWS + row], __float_as_uint(mx));
    }
}

// ================= K2: histogram segment + bf16(x) emit — full-GPU =================
__global__ __launch_bounds__(256) void k_hist2(const float* __restrict__ x, float* __restrict__ ws) {
    int row = blockIdx.x >> 3, seg = blockIdx.x & 7;
    int tid = threadIdx.x, wave = tid >> 6;
    const unsigned* mm = (const unsigned*)(ws + WS_MM);
    float mn = __uint_as_float(mm[row]), mx = __uint_as_float(mm[ROWS + row]);
    float w = (mx > mn) ? (mx - mn) : 1.0f;
    __shared__ unsigned bins[4][NBINS];
    for (int i = tid; i < 4 * NBINS; i += 256) bins[i / NBINS][i % NBINS] = 0u;
    __syncthreads();
    const float4* p = (const float4*)(x + (size_t)row * RLEN) + seg * SEGF4;
    short* xrow = (short*)(ws + WS_XBF) + (size_t)row * RLEN + (size_t)seg * SEGF4 * 4;
    unsigned* mybins = bins[wave & 3];
    for (int i = tid; i < SEGF4; i += 256) {
        float4 v = p[i];
        float e[4] = {v.x, v.y, v.z, v.w};
#pragma unroll
        for (int j = 0; j < 4; ++j) {
            // exact reference fp32 op sequence: (x-mn)/width*100 -> floor -> int -> clip
            int idx = (int)floorf((e[j] - mn) / w * 100.0f);
            idx = idx < 0 ? 0 : (idx > 99 ? 99 : idx);
            atomicAdd(&mybins[idx], 1u);
        }
        *(short4*)&xrow[4 * i] = make_short4(f2bf(v.x), f2bf(v.y), f2bf(v.z), f2bf(v.w));
    }
    __syncthreads();
    if (tid < NBINS) {
        unsigned s = bins[0][tid] + bins[1][tid] + bins[2][tid] + bins[3][tid];
        unsigned* gb = (unsigned*)(ws + WS_GB);
        atomicAdd(&gb[row * NBINS + tid], s);
    }
}

// ================= K3: bins (uint) -> float into h_in hist columns =================
__global__ __launch_bounds__(256) void k_binf(float* __restrict__ ws) {
    int i = blockIdx.x * 256 + threadIdx.x;        // 19200 = 75*256 exact
    const unsigned* gb = (const unsigned*)(ws + WS_GB);
    int row = i / NBINS, bin = i - row * NBINS;
    int b = row / 3, c = row - b * 3;
    ws[WS_HIN + b * HIN_W + NEMB + c * NBINS + bin] = (float)gb[i];
}

// ================= K4: GEMM partials = A(bf16) @ base_W.T (split-K, LDS-staged bf16 MFMA) =================
// grid (112, 8), block 256 = 4 waves, all 896 blocks co-resident (3.5/CU at 4/CU residency).
__global__ __launch_bounds__(256, 4) void k_gemm(const float* __restrict__ ws_all, const float* __restrict__ W,
                                                 float* __restrict__ part) {
    __shared__ short sA[2][64 * LDA];
    __shared__ short sB[2][64 * LDA];

    int kc = blockIdx.x;
    int n0 = blockIdx.y * NTILE;
    int tid = threadIdx.x;
    int wave = tid >> 6, lane = tid & 63;
    int l15 = lane & 15, quad = lane >> 4;

    const short* Abf = (const short*)(ws_all + WS_XBF);

    // A loader: slab = 64 rows x 8 slots of 8 shorts (16B); 512 slots, 2 passes of 256.
    int arow[2], acol[2];
#pragma unroll
    for (int pp = 0; pp < 2; ++pp) { int slot = pp * 256 + tid; arow[pp] = slot >> 3; acol[pp] = slot & 7; }
    // B loader: slab = 64 rows x 16 float4; 1024 slots, 4 passes of 256.
    int brow[4], bf4[4];
#pragma unroll
    for (int pp = 0; pp < 4; ++pp) { int slot = pp * 256 + tid; brow[pp] = slot >> 4; bf4[pp] = slot & 15; }

    const short* Ab = Abf + (size_t)kc * KC;                           // + row*KDIM + s*BK + col*8
    const float* Bb = W + (size_t)n0 * KDIM + (size_t)kc * KC;         // + row*KDIM + s*BK + f4*4

    f32x4 acc[4];
#pragma unroll
    for (int mt = 0; mt < 4; ++mt) acc[mt] = (f32x4){0.f, 0.f, 0.f, 0.f};

    bf16x8 pfA[2];
    float4 pfB[4];
    // prologue: slab 0
#pragma unroll
    for (int pp = 0; pp < 2; ++pp)
        pfA[pp] = *(const bf16x8*)(Ab + (size_t)arow[pp] * KDIM + acol[pp] * 8);
#pragma unroll
    for (int pp = 0; pp < 4; ++pp)
        pfB[pp] = *(const float4*)(Bb + (size_t)brow[pp] * KDIM + bf4[pp] * 4);
#pragma unroll
    for (int pp = 0; pp < 2; ++pp)
        *(bf16x8*)&sA[0][arow[pp] * LDA + acol[pp] * 8] = pfA[pp];
#pragma unroll
    for (int pp = 0; pp < 4; ++pp)
        *(short4*)&sB[0][brow[pp] * LDA + bf4[pp] * 4] =
            make_short4(f2bf(pfB[pp].x), f2bf(pfB[pp].y), f2bf(pfB[pp].z), f2bf(pfB[pp].w));
    __syncthreads();

    for (int s = 0; s < NSLAB; ++s) {
        int buf = s & 1;
        if (s + 1 < NSLAB) {   // issue next-slab loads: a full slab of compute hides them
            const short* An = Ab + (s + 1) * BK;
            const float* Bn = Bb + (s + 1) * BK;
#pragma unroll
            for (int pp = 0; pp < 2; ++pp)
                pfA[pp] = *(const bf16x8*)(An + (size_t)arow[pp] * KDIM + acol[pp] * 8);
#pragma unroll
            for (int pp = 0; pp < 4; ++pp)
                pfB[pp] = *(const float4*)(Bn + (size_t)brow[pp] * KDIM + bf4[pp] * 4);
        }
#pragma unroll
        for (int ks = 0; ks < 2; ++ks) {
            bf16x8 bf = *(const bf16x8*)&sB[buf][(wave * 16 + l15) * LDA + ks * 32 + quad * 8];
#pragma unroll
            for (int mt = 0; mt < 4; ++mt) {
                bf16x8 af = *(const bf16x8*)&sA[buf][(mt * 16 + l15) * LDA + ks * 32 + quad * 8];
                acc[mt] = __builtin_amdgcn_mfma_f32_16x16x32_bf16(af, bf, acc[mt], 0, 0, 0);
            }
        }
        if (s + 1 < NSLAB) {
            int nbuf = buf ^ 1;
#pragma unroll
            for (int pp = 0; pp < 2; ++pp)
                *(bf16x8*)&sA[nbuf][arow[pp] * LDA + acol[pp] * 8] = pfA[pp];
#pragma unroll
            for (int pp = 0; pp < 4; ++pp)
                *(short4*)&sB[nbuf][brow[pp] * LDA + bf4[pp] * 4] =
                    make_short4(f2bf(pfB[pp].x), f2bf(pfB[pp].y), f2bf(pfB[pp].z), f2bf(pfB[pp].w));
        }
        __syncthreads();
    }

    // C/D layout: col = lane&15 (n), row = quad*4 + reg (m)   [rounds 1-3 validated]
    float* pb = part + (size_t)kc * (BATCH * NEMB);
#pragma unroll
    for (int mt = 0; mt < 4; ++mt) {
        int n = n0 + wave * 16 + l15;
#pragma unroll
        for (int r = 0; r < 4; ++r) {
            int m = mt * 16 + quad * 4 + r;
            pb[m * NEMB + n] = acc[mt][r];
        }
    }
}

// ================= K5: reduce split-K partials + bias -> h_in[:, :512] =================
__global__ __launch_bounds__(256) void k_reduce(const float* __restrict__ part, const float* __restrict__ bias,
                                                float* __restrict__ hin) {
    __shared__ float sm[256];
    int tid = threadIdx.x;
    int o = blockIdx.x * 32 + (tid & 31);     // 32768 outputs
    int slice = tid >> 5;                     // 0..7; 112/8 = 14 iters exact
    float s = 0.f;
    for (int c = slice; c < NCHUNK; c += 8) s += part[(size_t)c * (BATCH * NEMB) + o];
    sm[tid] = s;
    __syncthreads();
    if (tid < 32) {
        float t = sm[tid];
#pragma unroll
        for (int sl = 1; sl < 8; ++sl) t += sm[sl * 32 + tid];
        int m = o >> 9, n = o & 511;
        hin[m * HIN_W + n] = t + bias[n];
    }
}

// ================= K6: h = relu(h_in @ hW.T + hb) — one wave per output =================
__global__ __launch_bounds__(256) void k_layer1(const float* __restrict__ hin, const float* __restrict__ hW,
                                                const float* __restrict__ hb, float* __restrict__ h) {
    int wave = threadIdx.x >> 6, lane = threadIdx.x & 63;
    int gid = blockIdx.x * 4 + wave;           // 25600 outputs
    int b = gid / HID, j = gid - b * HID;
    const float* hr = hin + b * HIN_W;
    const float* wr = hW + j * HIN_W;
    float s = 0.f;
    for (int k = lane; k < HIN_W; k += 64) s += hr[k] * wr[k];
#pragma unroll
    for (int m = 1; m < 64; m <<= 1) s += __shfl_xor(s, m, 64);
    if (lane == 0) h[b * HID + j] = fmaxf(s + hb[j], 0.f);
}

// ================= K7: heads layer-1 (st600 | age400 | gen400 concat) =================
__global__ __launch_bounds__(256) void k_heads1(const float* __restrict__ h,
                                                const float* __restrict__ stW1, const float* __restrict__ stb1,
                                                const float* __restrict__ ageW1, const float* __restrict__ ageb1,
                                                const float* __restrict__ genW1, const float* __restrict__ genb1,
                                                float* __restrict__ t) {
    int wave = threadIdx.x >> 6, lane = threadIdx.x & 63;
    int gid = blockIdx.x * 4 + wave;           // 89600 outputs
    int b = gid / 1400, o = gid - b * 1400;
    const float* wr; float bias;
    if (o < 600)       { wr = stW1  + (size_t)o * 400;          bias = stb1[o]; }
    else if (o < 1000) { wr = ageW1 + (size_t)(o - 600) * 400;  bias = ageb1[o - 600]; }
    else               { wr = genW1 + (size_t)(o - 1000) * 400; bias = genb1[o - 1000]; }
    const float* hr = h + b * HID;
    float s = 0.f;
    for (int k = lane; k < 400; k += 64) s += hr[k] * wr[k];
#pragma unroll
    for (int m = 1; m < 64; m <<= 1) s += __shfl_xor(s, m, 64);
    if (lane == 0) t[b * 1400 + o] = fmaxf(s + bias, 0.f);
}

// ================= K8: heads layer-2 + relu + softmax -> d_out =================
// 64 blocks x 256: 16 outputs x 16 lanes each.
__global__ __launch_bounds__(256) void k_heads2(const float* __restrict__ t,
                                                const float* __restrict__ stW2, const float* __restrict__ stb2,
                                                const float* __restrict__ ageW2, const float* __restrict__ ageb2,
                                                const float* __restrict__ genW2, const float* __restrict__ genb2,
                                                float* __restrict__ out) {
    int b = blockIdx.x;
    int tid = threadIdx.x;
    int o = tid >> 4, sub = tid & 15;          // 16 outputs x 16 lanes
    const float* tr = t + b * 1400;
    const float* wr; const float* tb; float bias; int Klen;
    if (o < 10)      { wr = stW2  + o * 600;        tb = tr;        bias = stb2[o];       Klen = 600; }
    else if (o < 14) { wr = ageW2 + (o - 10) * 400; tb = tr + 600;  bias = ageb2[o - 10]; Klen = 400; }
    else             { wr = genW2 + (o - 14) * 400; tb = tr + 1000; bias = genb2[o - 14]; Klen = 400; }
    float s = 0.f;
    for (int k = sub; k < Klen; k += 16) s += tb[k] * wr[k];
#pragma unroll
    for (int m = 1; m < 16; m <<= 1) s += __shfl_xor(s, m, 64);   // xor within aligned 16-lane group
    __shared__ float lg[16];
    if (sub == 0) lg[o] = fmaxf(s + bias, 0.f);   // relu(logits)
    __syncthreads();
    if (tid == 0) {         // softmax st -> out[b*10]
        float mx = lg[0];
        for (int i = 1; i < 10; ++i) mx = fmaxf(mx, lg[i]);
        float e[10], sum = 0.f;
        for (int i = 0; i < 10; ++i) { e[i] = expf(lg[i] - mx); sum += e[i]; }
        for (int i = 0; i < 10; ++i) out[b * 10 + i] = e[i] / sum;
    } else if (tid == 1) {  // softmax age -> out[640 + b*4]
        float mx = lg[10];
        for (int i = 1; i < 4; ++i) mx = fmaxf(mx, lg[10 + i]);
        float e[4], sum = 0.f;
        for (int i = 0; i < 4; ++i) { e[i] = expf(lg[10 + i] - mx); sum += e[i]; }
        for (int i = 0; i < 4; ++i) out[640 + b * 4 + i] = e[i] / sum;
    } else if (tid == 2) {  // softmax gender -> out[896 + b*2]
        float mx = fmaxf(lg[14], lg[15]);
        float e0 = expf(lg[14] - mx), e1 = expf(lg[15] - mx);
        float sum = e0 + e1;
        out[896 + b * 2 + 0] = e0 / sum;
        out[896 + b * 2 + 1] = e1 / sum;
    }
}

// ================= launch =================
extern "C" void kernel_launch(void* const* d_in, const int* in_sizes, int n_in,
                              void* d_out, int out_size, void* d_ws, size_t ws_size,
                              hipStream_t stream) {
    (void)in_sizes; (void)n_in; (void)out_size; (void)ws_size;
    const float* x      = (const float*)d_in[0];
    const float* base_W = (const float*)d_in[1];
    const float* base_b = (const float*)d_in[2];
    const float* hW     = (const float*)d_in[3];
    const float* hb     = (const float*)d_in[4];
    const float* stW1   = (const float*)d_in[5];
    const float* stb1   = (const float*)d_in[6];
    const float* stW2   = (const float*)d_in[7];
    const float* stb2   = (const float*)d_in[8];
    const float* ageW1  = (const float*)d_in[9];
    const float* ageb1  = (const float*)d_in[10];
    const float* ageW2  = (const float*)d_in[11];
    const float* ageb2  = (const float*)d_in[12];
    const float* genW1  = (const float*)d_in[13];
    const float* genb1  = (const float*)d_in[14];
    const float* genW2  = (const float*)d_in[15];
    const float* genb2  = (const float*)d_in[16];
    float* ws  = (float*)d_ws;
    float* out = (float*)d_out;

    k_init  <<<77, 256, 0, stream>>>(ws);
    k_minmax<<<ROWS * SEGS, 256, 0, stream>>>(x, ws);
    k_hist2 <<<ROWS * SEGS, 256, 0, stream>>>(x, ws);
    k_binf  <<<75, 256, 0, stream>>>(ws);
    k_gemm  <<<dim3(NCHUNK, NEMB / NTILE), 256, 0, stream>>>(ws, base_W, ws + WS_PART);
    k_reduce<<<(BATCH * NEMB) / 32, 256, 0, stream>>>(ws + WS_PART, base_b, ws + WS_HIN);
    k_layer1<<<(BATCH * HID) / 4, 256, 0, stream>>>(ws + WS_HIN, hW, hb, ws + WS_H);
    k_heads1<<<(BATCH * 1400) / 4, 256, 0, stream>>>(ws + WS_H, stW1, stb1, ageW1, ageb1, genW1, genb1, ws + WS_T);
    k_heads2<<<BATCH, 256, 0, stream>>>(ws + WS_T, stW2, stb2, ageW2, ageb2, genW2, genb2, out);
}